// Round 11
// baseline (865.297 us; speedup 1.0000x reference)
//
#include <hip/hip_runtime.h>
#include <hip/hip_bf16.h>

#define NN 100000
#define EE 400000
#define BB 1024
#define FXD 78
#define DIMC 32
#define VOCABN 26
#define SEQN 1000
#define PCONV 993
#define FLATN 31776
#define COMB 2304
#define NB_SC 391   // ceil(NN/256)

static __device__ __forceinline__ float relu_(float x) { return x > 0.f ? x : 0.f; }

// ---------------- GIN GEMM1: P = H' @ Wa  (H' optionally BN-affine on load) ----------------
template<int KC, bool TRANSFORM>
__global__ __launch_bounds__(256) void gin_gemm1(
    const float* __restrict__ H, const float* __restrict__ W, float* __restrict__ P,
    const float* __restrict__ sums, const float* __restrict__ gamma, const float* __restrict__ beta)
{
    __shared__ float As[32][KC + 1];
    __shared__ float Ws[KC][32];
    __shared__ float scale_s[32], shift_s[32];
    const int tid = threadIdx.x;
    const int row0 = blockIdx.x * 32;
    if (TRANSFORM) {
        if (tid < 32) {
            float mu = sums[tid] * (1.f / NN);
            float var = sums[32 + tid] * (1.f / NN) - mu * mu;
            float rs = rsqrtf(var + 1e-5f);
            float a = gamma[tid] * rs;
            scale_s[tid] = a;
            shift_s[tid] = beta[tid] - mu * a;
        }
    }
    for (int idx = tid; idx < KC * 32; idx += 256) Ws[idx / 32][idx % 32] = W[idx];
    __syncthreads();
    for (int idx = tid; idx < 32 * KC; idx += 256) {
        int r = idx / KC, k = idx % KC;
        float v = H[(row0 + r) * KC + k];
        if (TRANSFORM) v = v * scale_s[k] + shift_s[k];
        As[r][k] = v;
    }
    __syncthreads();
    const int col = tid & 31, rg = tid >> 5;
    float acc[4] = {0.f, 0.f, 0.f, 0.f};
    for (int k = 0; k < KC; ++k) {
        float w = Ws[k][col];
#pragma unroll
        for (int r = 0; r < 4; ++r) acc[r] += As[rg + 8 * r][k] * w;
    }
#pragma unroll
    for (int r = 0; r < 4; ++r) P[(row0 + rg + 8 * r) * 32 + col] = acc[r];
}

// ------------- GIN GEMM2: Y = relu( relu(P+AGG+ba) @ Wb + bb ), + per-block BN stat partials -------------
__global__ __launch_bounds__(256) void gin_gemm2(
    const float* __restrict__ P, const float* __restrict__ AGG, const float* __restrict__ W,
    const float* __restrict__ ba, const float* __restrict__ bb,
    float* __restrict__ Y, float* __restrict__ partials)
{
    __shared__ float As[32][33];
    __shared__ float Ws[32][32];
    __shared__ float red[8][32], red2[8][32];
    const int tid = threadIdx.x;
    const int row0 = blockIdx.x * 32;
    for (int idx = tid; idx < 1024; idx += 256) Ws[idx / 32][idx % 32] = W[idx];
    for (int idx = tid; idx < 1024; idx += 256) {
        int r = idx / 32, k = idx % 32;
        int g = (row0 + r) * 32 + k;
        As[r][k] = relu_(P[g] + AGG[g] + ba[k]);
    }
    __syncthreads();
    const int col = tid & 31, rg = tid >> 5;
    float acc[4] = {0.f, 0.f, 0.f, 0.f};
    for (int k = 0; k < 32; ++k) {
        float w = Ws[k][col];
#pragma unroll
        for (int r = 0; r < 4; ++r) acc[r] += As[rg + 8 * r][k] * w;
    }
    float s = 0.f, ss = 0.f;
#pragma unroll
    for (int r = 0; r < 4; ++r) {
        float y = relu_(acc[r] + bb[col]);
        Y[(row0 + rg + 8 * r) * 32 + col] = y;
        s += y; ss += y * y;
    }
    red[rg][col] = s; red2[rg][col] = ss;
    __syncthreads();
    if (tid < 32) {
        float t1 = 0.f, t2 = 0.f;
#pragma unroll
        for (int i = 0; i < 8; ++i) { t1 += red[i][tid]; t2 += red2[i][tid]; }
        partials[blockIdx.x * 64 + tid] = t1;
        partials[blockIdx.x * 64 + 32 + tid] = t2;
    }
}

// ================= CSR build (once per launch; edge_index is layer-invariant) =================
__global__ __launch_bounds__(256) void hist_kernel(const int* __restrict__ dst, int* __restrict__ deg)
{
    int e = blockIdx.x * 256 + threadIdx.x;
    if (e < EE) atomicAdd(&deg[dst[e]], 1);
}

__global__ __launch_bounds__(256) void scan1_kernel(
    const int* __restrict__ deg, int* __restrict__ scanex, int* __restrict__ bsums)
{
    __shared__ int tmp[2][256];
    int tid = threadIdx.x, g = blockIdx.x * 256 + tid;
    int v = (g < NN) ? deg[g] : 0;
    tmp[0][tid] = v;
    __syncthreads();
    int cur = 0;
    for (int off = 1; off < 256; off <<= 1) {
        int nxt = cur ^ 1;
        tmp[nxt][tid] = tmp[cur][tid] + ((tid >= off) ? tmp[cur][tid - off] : 0);
        cur = nxt;
        __syncthreads();
    }
    int incl = tmp[cur][tid];
    if (g < NN) scanex[g] = incl - v;
    if (tid == 255) bsums[blockIdx.x] = incl;
}

__global__ __launch_bounds__(512) void scan2_kernel(const int* __restrict__ bsums, int* __restrict__ bexcl)
{
    __shared__ int tmp[2][512];
    int tid = threadIdx.x;
    int v = (tid < NB_SC) ? bsums[tid] : 0;
    tmp[0][tid] = v;
    __syncthreads();
    int cur = 0;
    for (int off = 1; off < 512; off <<= 1) {
        int nxt = cur ^ 1;
        tmp[nxt][tid] = tmp[cur][tid] + ((tid >= off) ? tmp[cur][tid - off] : 0);
        cur = nxt;
        __syncthreads();
    }
    if (tid < NB_SC) bexcl[tid] = tmp[cur][tid] - v;
}

__global__ __launch_bounds__(256) void rowptr_kernel(
    const int* __restrict__ scanex, const int* __restrict__ bexcl, int* __restrict__ rowptr)
{
    int g = blockIdx.x * 256 + threadIdx.x;
    if (g < NN) rowptr[g] = scanex[g] + bexcl[g >> 8];
    if (g == 0) rowptr[NN] = EE;
}

__global__ __launch_bounds__(256) void fill_kernel(
    const int* __restrict__ src, const int* __restrict__ dst,
    const int* __restrict__ rowptr, int* __restrict__ cursor, int* __restrict__ eidx)
{
    int e = blockIdx.x * 256 + threadIdx.x;
    if (e >= EE) return;
    int d = dst[e];
    int slot = rowptr[d] + atomicAdd(&cursor[d], 1);
    eidx[slot] = src[e];
}

// ---------------- CSR gather: AGG[n] = sum_{e: dst=n} P[src[e]]  (no atomics, no memset) ----------------
__global__ __launch_bounds__(256) void gather_kernel(
    const int* __restrict__ rowptr, const int* __restrict__ eidx,
    const float* __restrict__ P, float* __restrict__ AGG)
{
    int t = blockIdx.x * 256 + threadIdx.x;
    int n = t >> 3, q = t & 7;
    if (n >= NN) return;
    int s = rowptr[n], e = rowptr[n + 1];
    float4 acc = make_float4(0.f, 0.f, 0.f, 0.f);
    for (int p = s; p < e; ++p) {
        int sn = eidx[p];
        float4 v = *(const float4*)&P[(size_t)sn * 32 + q * 4];
        acc.x += v.x; acc.y += v.y; acc.z += v.z; acc.w += v.w;
    }
    *(float4*)&AGG[(size_t)n * 32 + q * 4] = acc;
}

// ---------------- reduce per-block stat partials -> 64 sums ----------------
__global__ __launch_bounds__(256) void stat_reduce(const float* __restrict__ partials, float* __restrict__ sums)
{
    const int j = blockIdx.x; // 0..63
    float s = 0.f;
    for (int i = threadIdx.x; i < 3125; i += 256) s += partials[i * 64 + j];
#pragma unroll
    for (int off = 32; off > 0; off >>= 1) s += __shfl_down(s, off);
    __shared__ float wsum[4];
    int w = threadIdx.x >> 6, lane = threadIdx.x & 63;
    if (lane == 0) wsum[w] = s;
    __syncthreads();
    if (threadIdx.x == 0) sums[j] = wsum[0] + wsum[1] + wsum[2] + wsum[3];
}

// ---------------- global add pool with BN affine on load ----------------
__global__ __launch_bounds__(256) void pool_kernel(
    const float* __restrict__ Y, const int* __restrict__ batch,
    const float* __restrict__ sums, const float* __restrict__ gamma, const float* __restrict__ beta,
    float* __restrict__ XG)
{
    __shared__ float scale_s[32], shift_s[32];
    int tid = threadIdx.x;
    if (tid < 32) {
        float mu = sums[tid] * (1.f / NN);
        float var = sums[32 + tid] * (1.f / NN) - mu * mu;
        float rs = rsqrtf(var + 1e-5f);
        float a = gamma[tid] * rs;
        scale_s[tid] = a; shift_s[tid] = beta[tid] - mu * a;
    }
    __syncthreads();
    int idx = blockIdx.x * 256 + tid;
    if (idx >= NN * 32) return;
    int i = idx >> 5, c = idx & 31;
    float v = Y[idx] * scale_s[c] + shift_s[c];
    atomicAdd(&XG[batch[i] * 32 + c], v);
}

// ---------------- xg (B,32) @ (32,128) + bias, relu ----------------
__global__ __launch_bounds__(128) void fc_xd_kernel(
    const float* __restrict__ XG, const float* __restrict__ W, const float* __restrict__ b,
    float* __restrict__ XD)
{
    __shared__ float xs[32];
    int tid = threadIdx.x, blk = blockIdx.x;
    if (tid < 32) xs[tid] = XG[blk * 32 + tid];
    __syncthreads();
    float acc = b[tid];
    for (int k = 0; k < 32; ++k) acc += xs[k] * W[k * 128 + tid];
    XD[blk * 128 + tid] = relu_(acc);
}

// ---------------- M[f][v][k] = sum_c emb[v,c] * convw[f,c,k]  (layout for fused conv-GEMM) ----------------
__global__ __launch_bounds__(256) void mtable_kernel(
    const float* __restrict__ emb, const float* __restrict__ cw, float* __restrict__ M)
{
    int v = blockIdx.x, tid = threadIdx.x;
    int k = tid >> 5, f = tid & 31;
    float acc = 0.f;
    for (int c = 0; c < 128; ++c) acc += emb[v * 128 + c] * cw[f * 1024 + c * 8 + k];
    M[f * 208 + v * 8 + k] = acc;   // 26*8 = 208 floats per filter, contiguous
}

// ---------- fused conv + xt GEMM: per block (m-tile, filter f); A computed on the fly ----------
// out partial z-layout identical to gemm_v3 split-K: out + f*(1024*128)
__global__ __launch_bounds__(256) void xt_fused(
    const int* __restrict__ target, const float* __restrict__ M, const float* __restrict__ cb,
    const float* __restrict__ W, float* __restrict__ out)
{
    __shared__ float As[32][68];
    __shared__ float Ws[32][132];
    __shared__ int   toks[64][41];     // stride 41: coprime with 32 banks
    __shared__ float Ms[26 * 9];       // stride 9: coprime with 32 banks
    const int tid = threadIdx.x;
    const int m0 = blockIdx.x * 64;
    const int f  = blockIdx.z;
    const int tx = tid & 31, ty = tid >> 5;    // NG=32 col-groups, MR=8 rows/thread
    const float cbf = cb[f];

    for (int i = tid; i < 208; i += 256) Ms[(i >> 3) * 9 + (i & 7)] = M[f * 208 + i];
    __syncthreads();

    float4 acc[8];
#pragma unroll
    for (int i = 0; i < 8; ++i) acc[i] = make_float4(0.f, 0.f, 0.f, 0.f);

    for (int p0 = 0; p0 < PCONV; p0 += 32) {
        // stage token window [64][40] and W-tile [32][128]
#pragma unroll
        for (int t = 0; t < 10; ++t) {
            int idx = tid + t * 256;
            int r = idx / 40, c = idx - r * 40;
            int p = p0 + c;
            toks[r][c] = (p < SEQN) ? target[(size_t)(m0 + r) * SEQN + p] : 0;
        }
#pragma unroll
        for (int t = 0; t < 4; ++t) {
            int f4i = tid + t * 256;
            int kk = f4i >> 5, n4 = f4i & 31;
            float4 wv = make_float4(0.f, 0.f, 0.f, 0.f);
            if (p0 + kk < PCONV)
                wv = *(const float4*)&W[(size_t)(f * PCONV + p0 + kk) * 128 + 4 * n4];
            *(float4*)&Ws[kk][4 * n4] = wv;
        }
        __syncthreads();
        // compute A-tile = relu(conv) on the fly
#pragma unroll
        for (int t = 0; t < 8; ++t) {
            int idx = tid + t * 256;
            int r = idx & 63, kk = idx >> 6;
            int p = p0 + kk;
            float s = 0.f;
            if (p < PCONV) {
                s = cbf;
#pragma unroll
                for (int j = 0; j < 8; ++j)
                    s += Ms[toks[r][kk + j] * 9 + j];
                s = relu_(s);
            }
            As[kk][r] = s;
        }
        __syncthreads();
        // inner product (identical to gemm_v3<128>)
#pragma unroll
        for (int kk = 0; kk < 32; ++kk) {
            float4 wv = *(const float4*)&Ws[kk][4 * tx];
#pragma unroll
            for (int j = 0; j < 2; ++j) {
                float4 av = *(const float4*)&As[kk][8 * ty + 4 * j];
                float ar[4] = {av.x, av.y, av.z, av.w};
#pragma unroll
                for (int i = 0; i < 4; ++i) {
                    acc[4 * j + i].x += ar[i] * wv.x;
                    acc[4 * j + i].y += ar[i] * wv.y;
                    acc[4 * j + i].z += ar[i] * wv.z;
                    acc[4 * j + i].w += ar[i] * wv.w;
                }
            }
        }
        __syncthreads();
    }

    float* dst = out + (size_t)f * (size_t)(16 * 64) * 128;
#pragma unroll
    for (int i = 0; i < 8; ++i)
        *(float4*)&dst[(size_t)(m0 + 8 * ty + i) * 128 + 4 * tx] = acc[i];
}

// ---------------- gemm_v3: 64xTN tile, float4 staging, no bounds checks in main body, split-K ----------------
template<int TN>
__global__ __launch_bounds__(256) void gemm_v3(
    const float* __restrict__ A, const float* __restrict__ W,
    float* __restrict__ out, int lda, int ldw, int ldo, int k_end, int k_chunk)
{
    constexpr int NG = TN / 4;
    constexpr int MR = NG / 4;
    __shared__ float As[32][64 + 4];
    __shared__ float Ws[32][TN + 4];
    const int tid = threadIdx.x;
    const int m0 = blockIdx.x * 64, n0 = blockIdx.y * TN;
    const int kb = blockIdx.z * k_chunk;
    const int ke = min(kb + k_chunk, k_end);
    const int tx = tid % NG, ty = tid / NG;

    float4 acc[MR];
#pragma unroll
    for (int i = 0; i < MR; ++i) acc[i] = make_float4(0.f, 0.f, 0.f, 0.f);

    const int nk = (ke - kb) >> 5;
    for (int kit = 0; kit < nk; ++kit) {
        const int k0 = kb + kit * 32;
#pragma unroll
        for (int t = 0; t < 2; ++t) {
            int f4i = tid + t * 256;
            int r = f4i >> 3, c = f4i & 7;
            float4 v = *(const float4*)&A[(size_t)(m0 + r) * lda + k0 + 4 * c];
            As[4 * c + 0][r] = v.x; As[4 * c + 1][r] = v.y;
            As[4 * c + 2][r] = v.z; As[4 * c + 3][r] = v.w;
        }
#pragma unroll
        for (int t = 0; t < NG / 8; ++t) {
            int f4i = tid + t * 256;
            int kk = f4i / NG, n4 = f4i % NG;
            *(float4*)&Ws[kk][4 * n4] = *(const float4*)&W[(size_t)(k0 + kk) * ldw + n0 + 4 * n4];
        }
        __syncthreads();
#pragma unroll
        for (int kk = 0; kk < 32; ++kk) {
            float4 wv = *(const float4*)&Ws[kk][4 * tx];
#pragma unroll
            for (int j = 0; j < MR / 4; ++j) {
                float4 av = *(const float4*)&As[kk][MR * ty + 4 * j];
                float ar[4] = {av.x, av.y, av.z, av.w};
#pragma unroll
                for (int i = 0; i < 4; ++i) {
                    acc[4 * j + i].x += ar[i] * wv.x;
                    acc[4 * j + i].y += ar[i] * wv.y;
                    acc[4 * j + i].z += ar[i] * wv.z;
                    acc[4 * j + i].w += ar[i] * wv.w;
                }
            }
        }
        __syncthreads();
    }
    for (int k = kb + nk * 32; k < ke; ++k) {
        float4 wv = *(const float4*)&W[(size_t)k * ldw + n0 + 4 * tx];
#pragma unroll
        for (int i = 0; i < MR; ++i) {
            float a = A[(size_t)(m0 + MR * ty + i) * lda + k];
            acc[i].x += a * wv.x; acc[i].y += a * wv.y;
            acc[i].z += a * wv.z; acc[i].w += a * wv.w;
        }
    }

    float* dst = out + (size_t)blockIdx.z * (size_t)(gridDim.x * 64) * (size_t)ldo;
#pragma unroll
    for (int i = 0; i < MR; ++i)
        *(float4*)&dst[(size_t)(m0 + MR * ty + i) * ldo + n0 + 4 * tx] = acc[i];
}

// ---------------- split-K epilogue: out = relu(sum_z part[z] + bias) ----------------
__global__ __launch_bounds__(256) void splitk_reduce(
    const float* __restrict__ part, const float* __restrict__ bias,
    float* __restrict__ out, int MN, int N, int nz)
{
    int i4 = blockIdx.x * 256 + threadIdx.x;
    size_t base = (size_t)i4 * 4;
    if (base >= (size_t)MN) return;
    float4 s = make_float4(0.f, 0.f, 0.f, 0.f);
    for (int z = 0; z < nz; ++z) {
        float4 p = *(const float4*)&part[(size_t)z * MN + base];
        s.x += p.x; s.y += p.y; s.z += p.z; s.w += p.w;
    }
    int n0 = (int)(base % (size_t)N);
    float4 b = *(const float4*)&bias[n0];
    s.x = relu_(s.x + b.x); s.y = relu_(s.y + b.y);
    s.z = relu_(s.z + b.z); s.w = relu_(s.w + b.w);
    *(float4*)&out[base] = s;
}

// ---------------- concat [xd | xt | drug | protein] ----------------
__global__ __launch_bounds__(256) void concat_kernel(
    const float* __restrict__ XD, const float* __restrict__ XT,
    const float* __restrict__ drug, const float* __restrict__ prot, float* __restrict__ XC)
{
    int idx = blockIdx.x * 256 + threadIdx.x;
    if (idx >= BB * COMB) return;
    int b = idx / COMB, j = idx - b * COMB;
    float v;
    if (j < 128) v = XD[b * 128 + j];
    else if (j < 256) v = XT[b * 128 + (j - 128)];
    else if (j < 1280) v = drug[b * 1024 + (j - 256)];
    else v = prot[b * 1024 + (j - 1280)];
    XC[idx] = v;
}

// ---------------- final: out[b] = xc3[b,:] . out_w + out_b ----------------
__global__ __launch_bounds__(256) void out_kernel(
    const float* __restrict__ X, const float* __restrict__ ow, const float* __restrict__ ob,
    float* __restrict__ out)
{
    int wv = threadIdx.x >> 6, lane = threadIdx.x & 63;
    int b = blockIdx.x * 4 + wv;
    float acc = 0.f;
#pragma unroll
    for (int t = 0; t < 4; ++t) {
        int j = lane + t * 64;
        acc += X[b * 256 + j] * ow[j];
    }
#pragma unroll
    for (int off = 32; off > 0; off >>= 1) acc += __shfl_down(acc, off);
    if (lane == 0) out[b] = acc + ob[0];
}

extern "C" void kernel_launch(void* const* d_in, const int* in_sizes, int n_in,
                              void* d_out, int out_size, void* d_ws, size_t ws_size,
                              hipStream_t stream)
{
    (void)in_sizes; (void)n_in; (void)out_size; (void)ws_size;
    const float* x          = (const float*)d_in[0];
    const int*   edge       = (const int*)d_in[1];
    const int*   batch      = (const int*)d_in[2];
    const int*   target     = (const int*)d_in[3];
    const float* drug_lm    = (const float*)d_in[4];
    const float* protein_lm = (const float*)d_in[5];
    const float* w1a        = (const float*)d_in[6];
    const float* b1a        = (const float*)d_in[7];
    const float* w1b        = (const float*)d_in[8];
    const float* b1b        = (const float*)d_in[9];
    const float* gw_a       = (const float*)d_in[10];
    const float* gb_a       = (const float*)d_in[11];
    const float* gw_b       = (const float*)d_in[12];
    const float* gb_b       = (const float*)d_in[13];
    const float* bn_gamma   = (const float*)d_in[14];
    const float* bn_beta    = (const float*)d_in[15];
    const float* fc1_xd_w   = (const float*)d_in[16];
    const float* fc1_xd_b   = (const float*)d_in[17];
    const float* emb        = (const float*)d_in[18];
    const float* convxt_w   = (const float*)d_in[19];
    const float* convxt_b   = (const float*)d_in[20];
    const float* fc1_xt_w   = (const float*)d_in[21];
    const float* fc1_xt_b   = (const float*)d_in[22];
    const float* fc1_w      = (const float*)d_in[23];
    const float* fc1_b      = (const float*)d_in[24];
    const float* fc2_w      = (const float*)d_in[25];
    const float* fc2_b      = (const float*)d_in[26];
    const float* out_w      = (const float*)d_in[27];
    const float* out_b      = (const float*)d_in[28];
    float* out = (float*)d_out;

    char* ws = (char*)d_ws;
    size_t off = 0;
    auto alloc = [&](size_t bytes) -> void* {
        void* p = ws + off;
        off = (off + bytes + 255) & ~(size_t)255;
        return p;
    };
    float* P        = (float*)alloc((size_t)NN * 32 * 4);
    float* AGG      = (float*)alloc((size_t)NN * 32 * 4);
    float* Y0       = (float*)alloc((size_t)NN * 32 * 4);
    float* Y1       = (float*)alloc((size_t)NN * 32 * 4);
    float* partials = (float*)alloc((size_t)3125 * 64 * 4);
    float* sums     = (float*)alloc(64 * 4);
    float* XG       = (float*)alloc((size_t)BB * 32 * 4);
    float* XD       = (float*)alloc((size_t)BB * 128 * 4);
    float* Mt       = (float*)alloc((size_t)26 * 256 * 4);
    float* XT       = (float*)alloc((size_t)BB * 128 * 4);
    float* XC       = (float*)alloc((size_t)BB * COMB * 4);
    float* XC2      = (float*)alloc((size_t)BB * 1024 * 4);
    float* XC3      = (float*)alloc((size_t)BB * 256 * 4);
    float* SCR      = (float*)alloc((size_t)80 * 1024 * 1024);  // partials + CSR scratch

    // Scratch layout (single stream => strictly ordered):
    //  - xt_part (32*1024*128 f32 = 16.8MB) overlays P+AGG; used only BEFORE first GIN kernel.
    //  - fc1_part (16.8MB) / fc2_part (8.4MB) in SCR[0..26MB)
    //  - CSR buffers at SCR+48MB
    float* xt_part  = P;
    float* fc1_part = SCR;
    float* fc2_part = SCR + (size_t)4 * 1024 * 1024;
    char*  csr      = (char*)SCR + (size_t)48 * 1024 * 1024;
    int* deg    = (int*)csr;
    int* cursor = deg + NN;
    int* scanex = cursor + NN;
    int* bsums  = scanex + NN;
    int* bexcl  = bsums + 512;
    int* rowptr = bexcl + 512;
    int* eidx   = rowptr + (NN + 2);

    const int* src = edge;
    const int* dst = edge + EE;

    // ---- protein branch (conv fused into GEMM; no C buffer) ----
    mtable_kernel<<<26, 256, 0, stream>>>(emb, convxt_w, Mt);
    xt_fused<<<dim3(16, 1, 32), 256, 0, stream>>>(target, Mt, convxt_b, fc1_xt_w, xt_part);
    splitk_reduce<<<128, 256, 0, stream>>>(xt_part, fc1_xt_b, XT, BB * 128, 128, 32);

    // ---- CSR build ----
    hipMemsetAsync(deg, 0, (size_t)2 * NN * 4, stream);   // deg + cursor
    hist_kernel<<<1563, 256, 0, stream>>>(dst, deg);
    scan1_kernel<<<NB_SC, 256, 0, stream>>>(deg, scanex, bsums);
    scan2_kernel<<<1, 512, 0, stream>>>(bsums, bexcl);
    rowptr_kernel<<<NB_SC, 256, 0, stream>>>(scanex, bexcl, rowptr);
    fill_kernel<<<1563, 256, 0, stream>>>(src, dst, rowptr, cursor, eidx);

    // ---- GIN layer 1 (78 -> 32) ----
    gin_gemm1<78, false><<<3125, 256, 0, stream>>>(x, w1a, P, nullptr, nullptr, nullptr);
    gather_kernel<<<3125, 256, 0, stream>>>(rowptr, eidx, P, AGG);
    gin_gemm2<<<3125, 256, 0, stream>>>(P, AGG, w1b, b1a, b1b, Y0, partials);
    stat_reduce<<<64, 256, 0, stream>>>(partials, sums);

    // ---- GIN layers 2..5 ----
    float* yin = Y0; float* yout = Y1;
    for (int li = 0; li < 4; ++li) {
        gin_gemm1<32, true><<<3125, 256, 0, stream>>>(
            yin, gw_a + li * 1024, P, sums, bn_gamma + li * 32, bn_beta + li * 32);
        gather_kernel<<<3125, 256, 0, stream>>>(rowptr, eidx, P, AGG);
        gin_gemm2<<<3125, 256, 0, stream>>>(
            P, AGG, gw_b + li * 1024, gb_a + li * 32, gb_b + li * 32, yout, partials);
        stat_reduce<<<64, 256, 0, stream>>>(partials, sums);
        float* t = yin; yin = yout; yout = t;
    }

    // ---- pool + fc1_xd (applies layer-5 BN affine on load) ----
    hipMemsetAsync(XG, 0, (size_t)BB * 32 * 4, stream);
    pool_kernel<<<12500, 256, 0, stream>>>(yin, batch, sums, bn_gamma + 4 * 32, bn_beta + 4 * 32, XG);
    fc_xd_kernel<<<BB, 128, 0, stream>>>(XG, fc1_xd_w, fc1_xd_b, XD);

    // ---- combine + MLP head ----
    concat_kernel<<<9216, 256, 0, stream>>>(XD, XT, drug_lm, protein_lm, XC);
    gemm_v3<128><<<dim3(16, 8, 4), 256, 0, stream>>>(
        XC, fc1_w, fc1_part, COMB, 1024, 1024, COMB, 576);
    splitk_reduce<<<1024, 256, 0, stream>>>(fc1_part, fc1_b, XC2, BB * 1024, 1024, 4);
    gemm_v3<128><<<dim3(16, 2, 8), 256, 0, stream>>>(
        XC2, fc2_w, fc2_part, 1024, 256, 256, 1024, 128);
    splitk_reduce<<<256, 256, 0, stream>>>(fc2_part, fc2_b, XC3, BB * 256, 256, 8);
    out_kernel<<<256, 256, 0, stream>>>(XC3, out_w, out_b, out);
}

// Round 14
// 841.685 us; speedup vs baseline: 1.0281x; 1.0281x over previous
//
#include <hip/hip_runtime.h>
#include <hip/hip_bf16.h>

#define NN 100000
#define EE 400000
#define BB 1024
#define FXD 78
#define DIMC 32
#define VOCABN 26
#define SEQN 1000
#define PCONV 993
#define FLATN 31776
#define COMB 2304
#define NB_SC 391   // ceil(NN/256)

static __device__ __forceinline__ float relu_(float x) { return x > 0.f ? x : 0.f; }

// ---------------- GIN GEMM1: P = H' @ Wa  (H' optionally BN-affine on load) ----------------
template<int KC, bool TRANSFORM>
__global__ __launch_bounds__(256) void gin_gemm1(
    const float* __restrict__ H, const float* __restrict__ W, float* __restrict__ P,
    const float* __restrict__ sums, const float* __restrict__ gamma, const float* __restrict__ beta)
{
    __shared__ float As[32][KC + 1];
    __shared__ float Ws[KC][32];
    __shared__ float scale_s[32], shift_s[32];
    const int tid = threadIdx.x;
    const int row0 = blockIdx.x * 32;
    if (TRANSFORM) {
        if (tid < 32) {
            float mu = sums[tid] * (1.f / NN);
            float var = sums[32 + tid] * (1.f / NN) - mu * mu;
            float rs = rsqrtf(var + 1e-5f);
            float a = gamma[tid] * rs;
            scale_s[tid] = a;
            shift_s[tid] = beta[tid] - mu * a;
        }
    }
    for (int idx = tid; idx < KC * 32; idx += 256) Ws[idx / 32][idx % 32] = W[idx];
    __syncthreads();
    for (int idx = tid; idx < 32 * KC; idx += 256) {
        int r = idx / KC, k = idx % KC;
        float v = H[(row0 + r) * KC + k];
        if (TRANSFORM) v = v * scale_s[k] + shift_s[k];
        As[r][k] = v;
    }
    __syncthreads();
    const int col = tid & 31, rg = tid >> 5;
    float acc[4] = {0.f, 0.f, 0.f, 0.f};
    for (int k = 0; k < KC; ++k) {
        float w = Ws[k][col];
#pragma unroll
        for (int r = 0; r < 4; ++r) acc[r] += As[rg + 8 * r][k] * w;
    }
#pragma unroll
    for (int r = 0; r < 4; ++r) P[(row0 + rg + 8 * r) * 32 + col] = acc[r];
}

// ------- fused gather + GIN GEMM2: As = relu(P[self]+sum_nbr P+ba); Y = relu(As@Wb+bb); BN partials -------
__global__ __launch_bounds__(256) void gin_gather_gemm2(
    const int* __restrict__ rowptr, const int* __restrict__ eidx,
    const float* __restrict__ P, const float* __restrict__ W,
    const float* __restrict__ ba, const float* __restrict__ bb,
    float* __restrict__ Y, float* __restrict__ partials)
{
    __shared__ float As[32][33];
    __shared__ float Ws[32][32];
    __shared__ float red[8][32], red2[8][32];
    const int tid = threadIdx.x;
    const int row0 = blockIdx.x * 32;
    for (int idx = tid; idx < 1024; idx += 256) Ws[idx / 32][idx % 32] = W[idx];
    // gather phase: 8 threads per row, float4 channels
    {
        int r = tid >> 3, q = tid & 7;
        int n = row0 + r;
        int s = rowptr[n], e = rowptr[n + 1];
        float4 acc = *(const float4*)&P[(size_t)n * 32 + q * 4];   // self
        for (int p = s; p < e; ++p) {
            int sn = eidx[p];
            float4 v = *(const float4*)&P[(size_t)sn * 32 + q * 4];
            acc.x += v.x; acc.y += v.y; acc.z += v.z; acc.w += v.w;
        }
        float4 bv = *(const float4*)&ba[q * 4];
        As[r][4 * q + 0] = relu_(acc.x + bv.x);
        As[r][4 * q + 1] = relu_(acc.y + bv.y);
        As[r][4 * q + 2] = relu_(acc.z + bv.z);
        As[r][4 * q + 3] = relu_(acc.w + bv.w);
    }
    __syncthreads();
    const int col = tid & 31, rg = tid >> 5;
    float acc[4] = {0.f, 0.f, 0.f, 0.f};
    for (int k = 0; k < 32; ++k) {
        float w = Ws[k][col];
#pragma unroll
        for (int r = 0; r < 4; ++r) acc[r] += As[rg + 8 * r][k] * w;
    }
    float s = 0.f, ss = 0.f;
#pragma unroll
    for (int r = 0; r < 4; ++r) {
        float y = relu_(acc[r] + bb[col]);
        Y[(row0 + rg + 8 * r) * 32 + col] = y;
        s += y; ss += y * y;
    }
    red[rg][col] = s; red2[rg][col] = ss;
    __syncthreads();
    if (tid < 32) {
        float t1 = 0.f, t2 = 0.f;
#pragma unroll
        for (int i = 0; i < 8; ++i) { t1 += red[i][tid]; t2 += red2[i][tid]; }
        partials[blockIdx.x * 64 + tid] = t1;
        partials[blockIdx.x * 64 + 32 + tid] = t2;
    }
}

// ================= CSR build (once per launch; edge_index is layer-invariant) =================
__global__ __launch_bounds__(256) void hist_kernel(const int* __restrict__ dst, int* __restrict__ deg)
{
    int e = blockIdx.x * 256 + threadIdx.x;
    if (e < EE) atomicAdd(&deg[dst[e]], 1);
}

__global__ __launch_bounds__(256) void scan1_kernel(
    const int* __restrict__ deg, int* __restrict__ scanex, int* __restrict__ bsums)
{
    __shared__ int tmp[2][256];
    int tid = threadIdx.x, g = blockIdx.x * 256 + tid;
    int v = (g < NN) ? deg[g] : 0;
    tmp[0][tid] = v;
    __syncthreads();
    int cur = 0;
    for (int off = 1; off < 256; off <<= 1) {
        int nxt = cur ^ 1;
        tmp[nxt][tid] = tmp[cur][tid] + ((tid >= off) ? tmp[cur][tid - off] : 0);
        cur = nxt;
        __syncthreads();
    }
    int incl = tmp[cur][tid];
    if (g < NN) scanex[g] = incl - v;
    if (tid == 255) bsums[blockIdx.x] = incl;
}

__global__ __launch_bounds__(512) void scan2_kernel(const int* __restrict__ bsums, int* __restrict__ bexcl)
{
    __shared__ int tmp[2][512];
    int tid = threadIdx.x;
    int v = (tid < NB_SC) ? bsums[tid] : 0;
    tmp[0][tid] = v;
    __syncthreads();
    int cur = 0;
    for (int off = 1; off < 512; off <<= 1) {
        int nxt = cur ^ 1;
        tmp[nxt][tid] = tmp[cur][tid] + ((tid >= off) ? tmp[cur][tid - off] : 0);
        cur = nxt;
        __syncthreads();
    }
    if (tid < NB_SC) bexcl[tid] = tmp[cur][tid] - v;
}

__global__ __launch_bounds__(256) void rowptr_kernel(
    const int* __restrict__ scanex, const int* __restrict__ bexcl, int* __restrict__ rowptr)
{
    int g = blockIdx.x * 256 + threadIdx.x;
    if (g < NN) rowptr[g] = scanex[g] + bexcl[g >> 8];
    if (g == 0) rowptr[NN] = EE;
}

__global__ __launch_bounds__(256) void fill_kernel(
    const int* __restrict__ src, const int* __restrict__ dst,
    const int* __restrict__ rowptr, int* __restrict__ cursor, int* __restrict__ eidx)
{
    int e = blockIdx.x * 256 + threadIdx.x;
    if (e >= EE) return;
    int d = dst[e];
    int slot = rowptr[d] + atomicAdd(&cursor[d], 1);
    eidx[slot] = src[e];
}

// ---------------- reduce per-block stat partials -> 64 sums ----------------
__global__ __launch_bounds__(256) void stat_reduce(const float* __restrict__ partials, float* __restrict__ sums)
{
    const int j = blockIdx.x; // 0..63
    float s = 0.f;
    for (int i = threadIdx.x; i < 3125; i += 256) s += partials[i * 64 + j];
#pragma unroll
    for (int off = 32; off > 0; off >>= 1) s += __shfl_down(s, off);
    __shared__ float wsum[4];
    int w = threadIdx.x >> 6, lane = threadIdx.x & 63;
    if (lane == 0) wsum[w] = s;
    __syncthreads();
    if (threadIdx.x == 0) sums[j] = wsum[0] + wsum[1] + wsum[2] + wsum[3];
}

// ---------------- global add pool with BN affine on load ----------------
__global__ __launch_bounds__(256) void pool_kernel(
    const float* __restrict__ Y, const int* __restrict__ batch,
    const float* __restrict__ sums, const float* __restrict__ gamma, const float* __restrict__ beta,
    float* __restrict__ XG)
{
    __shared__ float scale_s[32], shift_s[32];
    int tid = threadIdx.x;
    if (tid < 32) {
        float mu = sums[tid] * (1.f / NN);
        float var = sums[32 + tid] * (1.f / NN) - mu * mu;
        float rs = rsqrtf(var + 1e-5f);
        float a = gamma[tid] * rs;
        scale_s[tid] = a; shift_s[tid] = beta[tid] - mu * a;
    }
    __syncthreads();
    int idx = blockIdx.x * 256 + tid;
    if (idx >= NN * 32) return;
    int i = idx >> 5, c = idx & 31;
    float v = Y[idx] * scale_s[c] + shift_s[c];
    atomicAdd(&XG[batch[i] * 32 + c], v);
}

// ---------------- xg (B,32) @ (32,128) + bias, relu ----------------
__global__ __launch_bounds__(128) void fc_xd_kernel(
    const float* __restrict__ XG, const float* __restrict__ W, const float* __restrict__ b,
    float* __restrict__ XD)
{
    __shared__ float xs[32];
    int tid = threadIdx.x, blk = blockIdx.x;
    if (tid < 32) xs[tid] = XG[blk * 32 + tid];
    __syncthreads();
    float acc = b[tid];
    for (int k = 0; k < 32; ++k) acc += xs[k] * W[k * 128 + tid];
    XD[blk * 128 + tid] = relu_(acc);
}

// ---------------- M[f][v][k] = sum_c emb[v,c] * convw[f,c,k]  (layout for fused conv-GEMM) ----------------
__global__ __launch_bounds__(256) void mtable_kernel(
    const float* __restrict__ emb, const float* __restrict__ cw, float* __restrict__ M)
{
    int v = blockIdx.x, tid = threadIdx.x;
    int k = tid >> 5, f = tid & 31;
    float acc = 0.f;
    for (int c = 0; c < 128; ++c) acc += emb[v * 128 + c] * cw[f * 1024 + c * 8 + k];
    M[f * 208 + v * 8 + k] = acc;   // 26*8 = 208 floats per filter, contiguous
}

// ---------- fused conv + xt GEMM v2: per block (m-tile, filter f, p-half h); z = f*2+h ----------
// out partial z-layout: out + z*(1024*128); nz = 64
__global__ __launch_bounds__(256) void xt_fused(
    const int* __restrict__ target, const float* __restrict__ M, const float* __restrict__ cb,
    const float* __restrict__ W, float* __restrict__ out)
{
    __shared__ float As[32][68];
    __shared__ float Ws[32][132];
    __shared__ int   toks[64][41];     // stride 41: coprime with 32 banks
    __shared__ float Ms[26 * 9];       // stride 9: coprime with 32 banks
    const int tid = threadIdx.x;
    const int m0 = blockIdx.x * 64;
    const int f  = blockIdx.z >> 1;
    const int h  = blockIdx.z & 1;
    const int pbase = h * 512;
    const int pend  = min(pbase + 512, PCONV);
    const int tx = tid & 31, ty = tid >> 5;    // NG=32 col-groups, MR=8 rows/thread
    const float cbf = cb[f];

    for (int i = tid; i < 208; i += 256) Ms[(i >> 3) * 9 + (i & 7)] = M[f * 208 + i];
    __syncthreads();

    float4 acc[8];
#pragma unroll
    for (int i = 0; i < 8; ++i) acc[i] = make_float4(0.f, 0.f, 0.f, 0.f);

    for (int p0 = pbase; p0 < pend; p0 += 32) {
        // stage token window [64][40] and W-tile [32][128]
#pragma unroll
        for (int t = 0; t < 10; ++t) {
            int idx = tid + t * 256;
            int r = idx / 40, c = idx - r * 40;
            int p = p0 + c;
            toks[r][c] = (p < SEQN) ? target[(size_t)(m0 + r) * SEQN + p] : 0;
        }
#pragma unroll
        for (int t = 0; t < 4; ++t) {
            int f4i = tid + t * 256;
            int kk = f4i >> 5, n4 = f4i & 31;
            float4 wv = make_float4(0.f, 0.f, 0.f, 0.f);
            if (p0 + kk < pend)
                wv = *(const float4*)&W[(size_t)(f * PCONV + p0 + kk) * 128 + 4 * n4];
            *(float4*)&Ws[kk][4 * n4] = wv;
        }
        __syncthreads();
        // compute A-tile = relu(conv) on the fly
#pragma unroll
        for (int t = 0; t < 8; ++t) {
            int idx = tid + t * 256;
            int r = idx & 63, kk = idx >> 6;
            int p = p0 + kk;
            float s = 0.f;
            if (p < pend) {
                s = cbf;
#pragma unroll
                for (int j = 0; j < 8; ++j)
                    s += Ms[toks[r][kk + j] * 9 + j];
                s = relu_(s);
            }
            As[kk][r] = s;
        }
        __syncthreads();
        // inner product
#pragma unroll
        for (int kk = 0; kk < 32; ++kk) {
            float4 wv = *(const float4*)&Ws[kk][4 * tx];
#pragma unroll
            for (int j = 0; j < 2; ++j) {
                float4 av = *(const float4*)&As[kk][8 * ty + 4 * j];
                float ar[4] = {av.x, av.y, av.z, av.w};
#pragma unroll
                for (int i = 0; i < 4; ++i) {
                    acc[4 * j + i].x += ar[i] * wv.x;
                    acc[4 * j + i].y += ar[i] * wv.y;
                    acc[4 * j + i].z += ar[i] * wv.z;
                    acc[4 * j + i].w += ar[i] * wv.w;
                }
            }
        }
        __syncthreads();
    }

    float* dst = out + (size_t)blockIdx.z * (size_t)(16 * 64) * 128;
#pragma unroll
    for (int i = 0; i < 8; ++i)
        *(float4*)&dst[(size_t)(m0 + 8 * ty + i) * 128 + 4 * tx] = acc[i];
}

// ---------------- gemm_v3: 64xTN tile, float4 staging, no bounds checks in main body, split-K ----------------
template<int TN>
__global__ __launch_bounds__(256) void gemm_v3(
    const float* __restrict__ A, const float* __restrict__ W,
    float* __restrict__ out, int lda, int ldw, int ldo, int k_end, int k_chunk)
{
    constexpr int NG = TN / 4;
    constexpr int MR = NG / 4;
    __shared__ float As[32][64 + 4];
    __shared__ float Ws[32][TN + 4];
    const int tid = threadIdx.x;
    const int m0 = blockIdx.x * 64, n0 = blockIdx.y * TN;
    const int kb = blockIdx.z * k_chunk;
    const int ke = min(kb + k_chunk, k_end);
    const int tx = tid % NG, ty = tid / NG;

    float4 acc[MR];
#pragma unroll
    for (int i = 0; i < MR; ++i) acc[i] = make_float4(0.f, 0.f, 0.f, 0.f);

    const int nk = (ke - kb) >> 5;
    for (int kit = 0; kit < nk; ++kit) {
        const int k0 = kb + kit * 32;
#pragma unroll
        for (int t = 0; t < 2; ++t) {
            int f4i = tid + t * 256;
            int r = f4i >> 3, c = f4i & 7;
            float4 v = *(const float4*)&A[(size_t)(m0 + r) * lda + k0 + 4 * c];
            As[4 * c + 0][r] = v.x; As[4 * c + 1][r] = v.y;
            As[4 * c + 2][r] = v.z; As[4 * c + 3][r] = v.w;
        }
#pragma unroll
        for (int t = 0; t < NG / 8; ++t) {
            int f4i = tid + t * 256;
            int kk = f4i / NG, n4 = f4i % NG;
            *(float4*)&Ws[kk][4 * n4] = *(const float4*)&W[(size_t)(k0 + kk) * ldw + n0 + 4 * n4];
        }
        __syncthreads();
#pragma unroll
        for (int kk = 0; kk < 32; ++kk) {
            float4 wv = *(const float4*)&Ws[kk][4 * tx];
#pragma unroll
            for (int j = 0; j < MR / 4; ++j) {
                float4 av = *(const float4*)&As[kk][MR * ty + 4 * j];
                float ar[4] = {av.x, av.y, av.z, av.w};
#pragma unroll
                for (int i = 0; i < 4; ++i) {
                    acc[4 * j + i].x += ar[i] * wv.x;
                    acc[4 * j + i].y += ar[i] * wv.y;
                    acc[4 * j + i].z += ar[i] * wv.z;
                    acc[4 * j + i].w += ar[i] * wv.w;
                }
            }
        }
        __syncthreads();
    }
    for (int k = kb + nk * 32; k < ke; ++k) {
        float4 wv = *(const float4*)&W[(size_t)k * ldw + n0 + 4 * tx];
#pragma unroll
        for (int i = 0; i < MR; ++i) {
            float a = A[(size_t)(m0 + MR * ty + i) * lda + k];
            acc[i].x += a * wv.x; acc[i].y += a * wv.y;
            acc[i].z += a * wv.z; acc[i].w += a * wv.w;
        }
    }

    float* dst = out + (size_t)blockIdx.z * (size_t)(gridDim.x * 64) * (size_t)ldo;
#pragma unroll
    for (int i = 0; i < MR; ++i)
        *(float4*)&dst[(size_t)(m0 + MR * ty + i) * ldo + n0 + 4 * tx] = acc[i];
}

// ---------------- split-K epilogue: out = relu(sum_z part[z] + bias) ----------------
__global__ __launch_bounds__(256) void splitk_reduce(
    const float* __restrict__ part, const float* __restrict__ bias,
    float* __restrict__ out, int MN, int N, int nz)
{
    int i4 = blockIdx.x * 256 + threadIdx.x;
    size_t base = (size_t)i4 * 4;
    if (base >= (size_t)MN) return;
    float4 s = make_float4(0.f, 0.f, 0.f, 0.f);
    for (int z = 0; z < nz; ++z) {
        float4 p = *(const float4*)&part[(size_t)z * MN + base];
        s.x += p.x; s.y += p.y; s.z += p.z; s.w += p.w;
    }
    int n0 = (int)(base % (size_t)N);
    float4 b = *(const float4*)&bias[n0];
    s.x = relu_(s.x + b.x); s.y = relu_(s.y + b.y);
    s.z = relu_(s.z + b.z); s.w = relu_(s.w + b.w);
    *(float4*)&out[base] = s;
}

// ---------------- concat [xd | xt | drug | protein] ----------------
__global__ __launch_bounds__(256) void concat_kernel(
    const float* __restrict__ XD, const float* __restrict__ XT,
    const float* __restrict__ drug, const float* __restrict__ prot, float* __restrict__ XC)
{
    int idx = blockIdx.x * 256 + threadIdx.x;
    if (idx >= BB * COMB) return;
    int b = idx / COMB, j = idx - b * COMB;
    float v;
    if (j < 128) v = XD[b * 128 + j];
    else if (j < 256) v = XT[b * 128 + (j - 128)];
    else if (j < 1280) v = drug[b * 1024 + (j - 256)];
    else v = prot[b * 1024 + (j - 1280)];
    XC[idx] = v;
}

// ---------------- final: out[b] = xc3[b,:] . out_w + out_b ----------------
__global__ __launch_bounds__(256) void out_kernel(
    const float* __restrict__ X, const float* __restrict__ ow, const float* __restrict__ ob,
    float* __restrict__ out)
{
    int wv = threadIdx.x >> 6, lane = threadIdx.x & 63;
    int b = blockIdx.x * 4 + wv;
    float acc = 0.f;
#pragma unroll
    for (int t = 0; t < 4; ++t) {
        int j = lane + t * 64;
        acc += X[b * 256 + j] * ow[j];
    }
#pragma unroll
    for (int off = 32; off > 0; off >>= 1) acc += __shfl_down(acc, off);
    if (lane == 0) out[b] = acc + ob[0];
}

extern "C" void kernel_launch(void* const* d_in, const int* in_sizes, int n_in,
                              void* d_out, int out_size, void* d_ws, size_t ws_size,
                              hipStream_t stream)
{
    (void)in_sizes; (void)n_in; (void)out_size; (void)ws_size;
    const float* x          = (const float*)d_in[0];
    const int*   edge       = (const int*)d_in[1];
    const int*   batch      = (const int*)d_in[2];
    const int*   target     = (const int*)d_in[3];
    const float* drug_lm    = (const float*)d_in[4];
    const float* protein_lm = (const float*)d_in[5];
    const float* w1a        = (const float*)d_in[6];
    const float* b1a        = (const float*)d_in[7];
    const float* w1b        = (const float*)d_in[8];
    const float* b1b        = (const float*)d_in[9];
    const float* gw_a       = (const float*)d_in[10];
    const float* gb_a       = (const float*)d_in[11];
    const float* gw_b       = (const float*)d_in[12];
    const float* gb_b       = (const float*)d_in[13];
    const float* bn_gamma   = (const float*)d_in[14];
    const float* bn_beta    = (const float*)d_in[15];
    const float* fc1_xd_w   = (const float*)d_in[16];
    const float* fc1_xd_b   = (const float*)d_in[17];
    const float* emb        = (const float*)d_in[18];
    const float* convxt_w   = (const float*)d_in[19];
    const float* convxt_b   = (const float*)d_in[20];
    const float* fc1_xt_w   = (const float*)d_in[21];
    const float* fc1_xt_b   = (const float*)d_in[22];
    const float* fc1_w      = (const float*)d_in[23];
    const float* fc1_b      = (const float*)d_in[24];
    const float* fc2_w      = (const float*)d_in[25];
    const float* fc2_b      = (const float*)d_in[26];
    const float* out_w      = (const float*)d_in[27];
    const float* out_b      = (const float*)d_in[28];
    float* out = (float*)d_out;

    char* ws = (char*)d_ws;
    size_t off = 0;
    auto alloc = [&](size_t bytes) -> void* {
        void* p = ws + off;
        off = (off + bytes + 255) & ~(size_t)255;
        return p;
    };
    float* P        = (float*)alloc((size_t)NN * 32 * 4);
    float* AGG      = (float*)alloc((size_t)NN * 32 * 4);   // dead (kept for xt_part span)
    float* Y0       = (float*)alloc((size_t)NN * 32 * 4);
    float* Y1       = (float*)alloc((size_t)NN * 32 * 4);
    float* partials = (float*)alloc((size_t)3125 * 64 * 4);
    float* sums     = (float*)alloc(64 * 4);
    float* XG       = (float*)alloc((size_t)BB * 32 * 4);
    float* XD       = (float*)alloc((size_t)BB * 128 * 4);
    float* Mt       = (float*)alloc((size_t)26 * 256 * 4);
    float* XT       = (float*)alloc((size_t)BB * 128 * 4);
    float* XC       = (float*)alloc((size_t)BB * COMB * 4);
    float* XC2      = (float*)alloc((size_t)BB * 1024 * 4);
    float* XC3      = (float*)alloc((size_t)BB * 256 * 4);
    float* SCR      = (float*)alloc((size_t)80 * 1024 * 1024);  // fc partials + CSR scratch

    // Scratch layout (single stream => strictly ordered):
    //  - xt_part (64*1024*128 f32 = 32MB) overlays P+AGG+Y0[0..6.4MB); all dead until
    //    splitk_reduce(xt) completes (first GIN write is P in gin_gemm1, after).
    //  - fc1_part (16.8MB) / fc2_part (8.4MB) in SCR[0..26MB)
    //  - CSR buffers at SCR+48MB
    float* xt_part  = P;
    float* fc1_part = SCR;
    float* fc2_part = SCR + (size_t)4 * 1024 * 1024;
    char*  csr      = (char*)SCR + (size_t)48 * 1024 * 1024;
    int* deg    = (int*)csr;
    int* cursor = deg + NN;
    int* scanex = cursor + NN;
    int* bsums  = scanex + NN;
    int* bexcl  = bsums + 512;
    int* rowptr = bexcl + 512;
    int* eidx   = rowptr + (NN + 2);

    const int* src = edge;
    const int* dst = edge + EE;

    // ---- protein branch (conv fused into GEMM; p-split z=64 for occupancy) ----
    mtable_kernel<<<26, 256, 0, stream>>>(emb, convxt_w, Mt);
    xt_fused<<<dim3(16, 1, 64), 256, 0, stream>>>(target, Mt, convxt_b, fc1_xt_w, xt_part);
    splitk_reduce<<<128, 256, 0, stream>>>(xt_part, fc1_xt_b, XT, BB * 128, 128, 64);

    // ---- CSR build ----
    hipMemsetAsync(deg, 0, (size_t)2 * NN * 4, stream);   // deg + cursor
    hist_kernel<<<1563, 256, 0, stream>>>(dst, deg);
    scan1_kernel<<<NB_SC, 256, 0, stream>>>(deg, scanex, bsums);
    scan2_kernel<<<1, 512, 0, stream>>>(bsums, bexcl);
    rowptr_kernel<<<NB_SC, 256, 0, stream>>>(scanex, bexcl, rowptr);
    fill_kernel<<<1563, 256, 0, stream>>>(src, dst, rowptr, cursor, eidx);

    // ---- GIN layer 1 (78 -> 32) ----
    gin_gemm1<78, false><<<3125, 256, 0, stream>>>(x, w1a, P, nullptr, nullptr, nullptr);
    gin_gather_gemm2<<<3125, 256, 0, stream>>>(rowptr, eidx, P, w1b, b1a, b1b, Y0, partials);
    stat_reduce<<<64, 256, 0, stream>>>(partials, sums);

    // ---- GIN layers 2..5 ----
    float* yin = Y0; float* yout = Y1;
    for (int li = 0; li < 4; ++li) {
        gin_gemm1<32, true><<<3125, 256, 0, stream>>>(
            yin, gw_a + li * 1024, P, sums, bn_gamma + li * 32, bn_beta + li * 32);
        gin_gather_gemm2<<<3125, 256, 0, stream>>>(
            rowptr, eidx, P, gw_b + li * 1024, gb_a + li * 32, gb_b + li * 32, yout, partials);
        stat_reduce<<<64, 256, 0, stream>>>(partials, sums);
        float* t = yin; yin = yout; yout = t;
    }

    // ---- pool + fc1_xd (applies layer-5 BN affine on load) ----
    hipMemsetAsync(XG, 0, (size_t)BB * 32 * 4, stream);
    pool_kernel<<<12500, 256, 0, stream>>>(yin, batch, sums, bn_gamma + 4 * 32, bn_beta + 4 * 32, XG);
    fc_xd_kernel<<<BB, 128, 0, stream>>>(XG, fc1_xd_w, fc1_xd_b, XD);

    // ---- combine + MLP head ----
    concat_kernel<<<9216, 256, 0, stream>>>(XD, XT, drug_lm, protein_lm, XC);
    gemm_v3<128><<<dim3(16, 8, 4), 256, 0, stream>>>(
        XC, fc1_w, fc1_part, COMB, 1024, 1024, COMB, 576);
    splitk_reduce<<<1024, 256, 0, stream>>>(fc1_part, fc1_b, XC2, BB * 1024, 1024, 4);
    gemm_v3<128><<<dim3(16, 2, 8), 256, 0, stream>>>(
        XC2, fc2_w, fc2_part, 1024, 256, 256, 1024, 128);
    splitk_reduce<<<256, 256, 0, stream>>>(fc2_part, fc2_b, XC3, BB * 256, 256, 8);
    out_kernel<<<256, 256, 0, stream>>>(XC3, out_w, out_b, out);
}

// Round 15
// 777.358 us; speedup vs baseline: 1.1131x; 1.0828x over previous
//
#include <hip/hip_runtime.h>
#include <hip/hip_bf16.h>

#define NN 100000
#define EE 400000
#define BB 1024
#define FXD 78
#define DIMC 32
#define VOCABN 26
#define SEQN 1000
#define PCONV 993
#define FLATN 31776
#define COMB 2304
#define NB_SC 391   // ceil(NN/256)

static __device__ __forceinline__ float relu_(float x) { return x > 0.f ? x : 0.f; }

// ---------------- GIN GEMM1: P = H' @ Wa  (H' optionally BN-affine on load) ----------------
template<int KC, bool TRANSFORM>
__global__ __launch_bounds__(256) void gin_gemm1(
    const float* __restrict__ H, const float* __restrict__ W, float* __restrict__ P,
    const float* __restrict__ sums, const float* __restrict__ gamma, const float* __restrict__ beta)
{
    __shared__ float As[32][KC + 1];
    __shared__ float Ws[KC][32];
    __shared__ float scale_s[32], shift_s[32];
    const int tid = threadIdx.x;
    const int row0 = blockIdx.x * 32;
    if (TRANSFORM) {
        if (tid < 32) {
            float mu = sums[tid] * (1.f / NN);
            float var = sums[32 + tid] * (1.f / NN) - mu * mu;
            float rs = rsqrtf(var + 1e-5f);
            float a = gamma[tid] * rs;
            scale_s[tid] = a;
            shift_s[tid] = beta[tid] - mu * a;
        }
    }
    for (int idx = tid; idx < KC * 32; idx += 256) Ws[idx / 32][idx % 32] = W[idx];
    __syncthreads();
    for (int idx = tid; idx < 32 * KC; idx += 256) {
        int r = idx / KC, k = idx % KC;
        float v = H[(row0 + r) * KC + k];
        if (TRANSFORM) v = v * scale_s[k] + shift_s[k];
        As[r][k] = v;
    }
    __syncthreads();
    const int col = tid & 31, rg = tid >> 5;
    float acc[4] = {0.f, 0.f, 0.f, 0.f};
    for (int k = 0; k < KC; ++k) {
        float w = Ws[k][col];
#pragma unroll
        for (int r = 0; r < 4; ++r) acc[r] += As[rg + 8 * r][k] * w;
    }
#pragma unroll
    for (int r = 0; r < 4; ++r) P[(row0 + rg + 8 * r) * 32 + col] = acc[r];
}

// ------- fused gather + GIN GEMM2: As = relu(P[self]+sum_nbr P+ba); Y = relu(As@Wb+bb); BN partials -------
__global__ __launch_bounds__(256) void gin_gather_gemm2(
    const int* __restrict__ rowptr, const int* __restrict__ eidx,
    const float* __restrict__ P, const float* __restrict__ W,
    const float* __restrict__ ba, const float* __restrict__ bb,
    float* __restrict__ Y, float* __restrict__ partials)
{
    __shared__ float As[32][33];
    __shared__ float Ws[32][32];
    __shared__ float red[8][32], red2[8][32];
    const int tid = threadIdx.x;
    const int row0 = blockIdx.x * 32;
    for (int idx = tid; idx < 1024; idx += 256) Ws[idx / 32][idx % 32] = W[idx];
    // gather phase: 8 threads per row, float4 channels
    {
        int r = tid >> 3, q = tid & 7;
        int n = row0 + r;
        int s = rowptr[n], e = rowptr[n + 1];
        float4 acc = *(const float4*)&P[(size_t)n * 32 + q * 4];   // self
        for (int p = s; p < e; ++p) {
            int sn = eidx[p];
            float4 v = *(const float4*)&P[(size_t)sn * 32 + q * 4];
            acc.x += v.x; acc.y += v.y; acc.z += v.z; acc.w += v.w;
        }
        float4 bv = *(const float4*)&ba[q * 4];
        As[r][4 * q + 0] = relu_(acc.x + bv.x);
        As[r][4 * q + 1] = relu_(acc.y + bv.y);
        As[r][4 * q + 2] = relu_(acc.z + bv.z);
        As[r][4 * q + 3] = relu_(acc.w + bv.w);
    }
    __syncthreads();
    const int col = tid & 31, rg = tid >> 5;
    float acc[4] = {0.f, 0.f, 0.f, 0.f};
    for (int k = 0; k < 32; ++k) {
        float w = Ws[k][col];
#pragma unroll
        for (int r = 0; r < 4; ++r) acc[r] += As[rg + 8 * r][k] * w;
    }
    float s = 0.f, ss = 0.f;
#pragma unroll
    for (int r = 0; r < 4; ++r) {
        float y = relu_(acc[r] + bb[col]);
        Y[(row0 + rg + 8 * r) * 32 + col] = y;
        s += y; ss += y * y;
    }
    red[rg][col] = s; red2[rg][col] = ss;
    __syncthreads();
    if (tid < 32) {
        float t1 = 0.f, t2 = 0.f;
#pragma unroll
        for (int i = 0; i < 8; ++i) { t1 += red[i][tid]; t2 += red2[i][tid]; }
        partials[blockIdx.x * 64 + tid] = t1;
        partials[blockIdx.x * 64 + 32 + tid] = t2;
    }
}

// ================= CSR build (once per launch; edge_index is layer-invariant) =================
__global__ __launch_bounds__(256) void hist_kernel(const int* __restrict__ dst, int* __restrict__ deg)
{
    int e = blockIdx.x * 256 + threadIdx.x;
    if (e < EE) atomicAdd(&deg[dst[e]], 1);
}

__global__ __launch_bounds__(256) void scan1_kernel(
    const int* __restrict__ deg, int* __restrict__ scanex, int* __restrict__ bsums)
{
    __shared__ int tmp[2][256];
    int tid = threadIdx.x, g = blockIdx.x * 256 + tid;
    int v = (g < NN) ? deg[g] : 0;
    tmp[0][tid] = v;
    __syncthreads();
    int cur = 0;
    for (int off = 1; off < 256; off <<= 1) {
        int nxt = cur ^ 1;
        tmp[nxt][tid] = tmp[cur][tid] + ((tid >= off) ? tmp[cur][tid - off] : 0);
        cur = nxt;
        __syncthreads();
    }
    int incl = tmp[cur][tid];
    if (g < NN) scanex[g] = incl - v;
    if (tid == 255) bsums[blockIdx.x] = incl;
}

__global__ __launch_bounds__(512) void scan2_kernel(const int* __restrict__ bsums, int* __restrict__ bexcl)
{
    __shared__ int tmp[2][512];
    int tid = threadIdx.x;
    int v = (tid < NB_SC) ? bsums[tid] : 0;
    tmp[0][tid] = v;
    __syncthreads();
    int cur = 0;
    for (int off = 1; off < 512; off <<= 1) {
        int nxt = cur ^ 1;
        tmp[nxt][tid] = tmp[cur][tid] + ((tid >= off) ? tmp[cur][tid - off] : 0);
        cur = nxt;
        __syncthreads();
    }
    if (tid < NB_SC) bexcl[tid] = tmp[cur][tid] - v;
}

__global__ __launch_bounds__(256) void rowptr_kernel(
    const int* __restrict__ scanex, const int* __restrict__ bexcl, int* __restrict__ rowptr)
{
    int g = blockIdx.x * 256 + threadIdx.x;
    if (g < NN) rowptr[g] = scanex[g] + bexcl[g >> 8];
    if (g == 0) rowptr[NN] = EE;
}

__global__ __launch_bounds__(256) void fill_kernel(
    const int* __restrict__ src, const int* __restrict__ dst,
    const int* __restrict__ rowptr, int* __restrict__ cursor, int* __restrict__ eidx)
{
    int e = blockIdx.x * 256 + threadIdx.x;
    if (e >= EE) return;
    int d = dst[e];
    int slot = rowptr[d] + atomicAdd(&cursor[d], 1);
    eidx[slot] = src[e];
}

// ---------------- reduce per-block stat partials -> 64 sums ----------------
__global__ __launch_bounds__(256) void stat_reduce(const float* __restrict__ partials, float* __restrict__ sums)
{
    const int j = blockIdx.x; // 0..63
    float s = 0.f;
    for (int i = threadIdx.x; i < 3125; i += 256) s += partials[i * 64 + j];
#pragma unroll
    for (int off = 32; off > 0; off >>= 1) s += __shfl_down(s, off);
    __shared__ float wsum[4];
    int w = threadIdx.x >> 6, lane = threadIdx.x & 63;
    if (lane == 0) wsum[w] = s;
    __syncthreads();
    if (threadIdx.x == 0) sums[j] = wsum[0] + wsum[1] + wsum[2] + wsum[3];
}

// ---------------- global add pool with BN affine on load ----------------
__global__ __launch_bounds__(256) void pool_kernel(
    const float* __restrict__ Y, const int* __restrict__ batch,
    const float* __restrict__ sums, const float* __restrict__ gamma, const float* __restrict__ beta,
    float* __restrict__ XG)
{
    __shared__ float scale_s[32], shift_s[32];
    int tid = threadIdx.x;
    if (tid < 32) {
        float mu = sums[tid] * (1.f / NN);
        float var = sums[32 + tid] * (1.f / NN) - mu * mu;
        float rs = rsqrtf(var + 1e-5f);
        float a = gamma[tid] * rs;
        scale_s[tid] = a; shift_s[tid] = beta[tid] - mu * a;
    }
    __syncthreads();
    int idx = blockIdx.x * 256 + tid;
    if (idx >= NN * 32) return;
    int i = idx >> 5, c = idx & 31;
    float v = Y[idx] * scale_s[c] + shift_s[c];
    atomicAdd(&XG[batch[i] * 32 + c], v);
}

// ---------------- xg (B,32) @ (32,128) + bias, relu ----------------
__global__ __launch_bounds__(128) void fc_xd_kernel(
    const float* __restrict__ XG, const float* __restrict__ W, const float* __restrict__ b,
    float* __restrict__ XD)
{
    __shared__ float xs[32];
    int tid = threadIdx.x, blk = blockIdx.x;
    if (tid < 32) xs[tid] = XG[blk * 32 + tid];
    __syncthreads();
    float acc = b[tid];
    for (int k = 0; k < 32; ++k) acc += xs[k] * W[k * 128 + tid];
    XD[blk * 128 + tid] = relu_(acc);
}

// ---------------- M[v,k,f] = sum_c emb[v,c] * convw[f,c,k]  (conv_kernel layout) ----------------
__global__ __launch_bounds__(256) void mtable_kernel(
    const float* __restrict__ emb, const float* __restrict__ cw, float* __restrict__ M)
{
    int v = blockIdx.x, tid = threadIdx.x;
    int k = tid >> 5, f = tid & 31;
    float acc = 0.f;
    for (int c = 0; c < 128; ++c) acc += emb[v * 128 + c] * cw[f * 1024 + c * 8 + k];
    M[v * 256 + k * 32 + f] = acc;
}

// ---------------- conv via table: C[b, f*993+p] = relu(bias[f] + sum_k M[tok[p+k],k,f]) ----------------
__global__ __launch_bounds__(256) void conv_kernel(
    const int* __restrict__ target, const float* __restrict__ M, const float* __restrict__ cb,
    float* __restrict__ C)
{
    __shared__ float Ms[26 * 265];
    __shared__ int toks[136];
    int tid = threadIdx.x;
    int b = blockIdx.y, p0 = blockIdx.x * 128;
    for (int idx = tid; idx < 6656; idx += 256) {
        int v = idx >> 8, rem = idx & 255, k = rem >> 5, f = rem & 31;
        Ms[v * 265 + k * 33 + f] = M[idx];
    }
    for (int t = tid; t < 135; t += 256) {
        int p = p0 + t;
        toks[t] = (p < SEQN) ? target[b * SEQN + p] : 0;
    }
    __syncthreads();
    int pl = tid & 31, sub = tid >> 5;
    for (int it = 0; it < 16; ++it) {
        int chunk = it * 8 + sub;
        int f = chunk >> 2, pb = chunk & 3;
        int p = p0 + pb * 32 + pl;
        if (p < PCONV) {
            float acc = cb[f];
            int psub = pb * 32 + pl;
#pragma unroll
            for (int k = 0; k < 8; ++k) {
                int tok = toks[psub + k];
                acc += Ms[tok * 265 + k * 33 + f];
            }
            C[(size_t)b * FLATN + f * PCONV + p] = relu_(acc);
        }
    }
}

// ---------------- gemm_v3: 64xTN tile, float4 staging, no bounds checks in main body, split-K ----------------
template<int TN>
__global__ __launch_bounds__(256) void gemm_v3(
    const float* __restrict__ A, const float* __restrict__ W,
    float* __restrict__ out, int lda, int ldw, int ldo, int k_end, int k_chunk)
{
    constexpr int NG = TN / 4;
    constexpr int MR = NG / 4;
    __shared__ float As[32][64 + 4];
    __shared__ float Ws[32][TN + 4];
    const int tid = threadIdx.x;
    const int m0 = blockIdx.x * 64, n0 = blockIdx.y * TN;
    const int kb = blockIdx.z * k_chunk;
    const int ke = min(kb + k_chunk, k_end);
    const int tx = tid % NG, ty = tid / NG;

    float4 acc[MR];
#pragma unroll
    for (int i = 0; i < MR; ++i) acc[i] = make_float4(0.f, 0.f, 0.f, 0.f);

    const int nk = (ke - kb) >> 5;
    for (int kit = 0; kit < nk; ++kit) {
        const int k0 = kb + kit * 32;
#pragma unroll
        for (int t = 0; t < 2; ++t) {
            int f4i = tid + t * 256;
            int r = f4i >> 3, c = f4i & 7;
            float4 v = *(const float4*)&A[(size_t)(m0 + r) * lda + k0 + 4 * c];
            As[4 * c + 0][r] = v.x; As[4 * c + 1][r] = v.y;
            As[4 * c + 2][r] = v.z; As[4 * c + 3][r] = v.w;
        }
#pragma unroll
        for (int t = 0; t < NG / 8; ++t) {
            int f4i = tid + t * 256;
            int kk = f4i / NG, n4 = f4i % NG;
            *(float4*)&Ws[kk][4 * n4] = *(const float4*)&W[(size_t)(k0 + kk) * ldw + n0 + 4 * n4];
        }
        __syncthreads();
#pragma unroll
        for (int kk = 0; kk < 32; ++kk) {
            float4 wv = *(const float4*)&Ws[kk][4 * tx];
#pragma unroll
            for (int j = 0; j < MR / 4; ++j) {
                float4 av = *(const float4*)&As[kk][MR * ty + 4 * j];
                float ar[4] = {av.x, av.y, av.z, av.w};
#pragma unroll
                for (int i = 0; i < 4; ++i) {
                    acc[4 * j + i].x += ar[i] * wv.x;
                    acc[4 * j + i].y += ar[i] * wv.y;
                    acc[4 * j + i].z += ar[i] * wv.z;
                    acc[4 * j + i].w += ar[i] * wv.w;
                }
            }
        }
        __syncthreads();
    }
    for (int k = kb + nk * 32; k < ke; ++k) {
        float4 wv = *(const float4*)&W[(size_t)k * ldw + n0 + 4 * tx];
#pragma unroll
        for (int i = 0; i < MR; ++i) {
            float a = A[(size_t)(m0 + MR * ty + i) * lda + k];
            acc[i].x += a * wv.x; acc[i].y += a * wv.y;
            acc[i].z += a * wv.z; acc[i].w += a * wv.w;
        }
    }

    float* dst = out + (size_t)blockIdx.z * (size_t)(gridDim.x * 64) * (size_t)ldo;
#pragma unroll
    for (int i = 0; i < MR; ++i)
        *(float4*)&dst[(size_t)(m0 + MR * ty + i) * ldo + n0 + 4 * tx] = acc[i];
}

// ---------------- split-K epilogue: out = relu(sum_z part[z] + bias) ----------------
__global__ __launch_bounds__(256) void splitk_reduce(
    const float* __restrict__ part, const float* __restrict__ bias,
    float* __restrict__ out, int MN, int N, int nz)
{
    int i4 = blockIdx.x * 256 + threadIdx.x;
    size_t base = (size_t)i4 * 4;
    if (base >= (size_t)MN) return;
    float4 s = make_float4(0.f, 0.f, 0.f, 0.f);
    for (int z = 0; z < nz; ++z) {
        float4 p = *(const float4*)&part[(size_t)z * MN + base];
        s.x += p.x; s.y += p.y; s.z += p.z; s.w += p.w;
    }
    int n0 = (int)(base % (size_t)N);
    float4 b = *(const float4*)&bias[n0];
    s.x = relu_(s.x + b.x); s.y = relu_(s.y + b.y);
    s.z = relu_(s.z + b.z); s.w = relu_(s.w + b.w);
    *(float4*)&out[base] = s;
}

// ---------------- concat [xd | xt | drug | protein] ----------------
__global__ __launch_bounds__(256) void concat_kernel(
    const float* __restrict__ XD, const float* __restrict__ XT,
    const float* __restrict__ drug, const float* __restrict__ prot, float* __restrict__ XC)
{
    int idx = blockIdx.x * 256 + threadIdx.x;
    if (idx >= BB * COMB) return;
    int b = idx / COMB, j = idx - b * COMB;
    float v;
    if (j < 128) v = XD[b * 128 + j];
    else if (j < 256) v = XT[b * 128 + (j - 128)];
    else if (j < 1280) v = drug[b * 1024 + (j - 256)];
    else v = prot[b * 1024 + (j - 1280)];
    XC[idx] = v;
}

// ---------------- final: out[b] = xc3[b,:] . out_w + out_b ----------------
__global__ __launch_bounds__(256) void out_kernel(
    const float* __restrict__ X, const float* __restrict__ ow, const float* __restrict__ ob,
    float* __restrict__ out)
{
    int wv = threadIdx.x >> 6, lane = threadIdx.x & 63;
    int b = blockIdx.x * 4 + wv;
    float acc = 0.f;
#pragma unroll
    for (int t = 0; t < 4; ++t) {
        int j = lane + t * 64;
        acc += X[b * 256 + j] * ow[j];
    }
#pragma unroll
    for (int off = 32; off > 0; off >>= 1) acc += __shfl_down(acc, off);
    if (lane == 0) out[b] = acc + ob[0];
}

extern "C" void kernel_launch(void* const* d_in, const int* in_sizes, int n_in,
                              void* d_out, int out_size, void* d_ws, size_t ws_size,
                              hipStream_t stream)
{
    (void)in_sizes; (void)n_in; (void)out_size; (void)ws_size;
    const float* x          = (const float*)d_in[0];
    const int*   edge       = (const int*)d_in[1];
    const int*   batch      = (const int*)d_in[2];
    const int*   target     = (const int*)d_in[3];
    const float* drug_lm    = (const float*)d_in[4];
    const float* protein_lm = (const float*)d_in[5];
    const float* w1a        = (const float*)d_in[6];
    const float* b1a        = (const float*)d_in[7];
    const float* w1b        = (const float*)d_in[8];
    const float* b1b        = (const float*)d_in[9];
    const float* gw_a       = (const float*)d_in[10];
    const float* gb_a       = (const float*)d_in[11];
    const float* gw_b       = (const float*)d_in[12];
    const float* gb_b       = (const float*)d_in[13];
    const float* bn_gamma   = (const float*)d_in[14];
    const float* bn_beta    = (const float*)d_in[15];
    const float* fc1_xd_w   = (const float*)d_in[16];
    const float* fc1_xd_b   = (const float*)d_in[17];
    const float* emb        = (const float*)d_in[18];
    const float* convxt_w   = (const float*)d_in[19];
    const float* convxt_b   = (const float*)d_in[20];
    const float* fc1_xt_w   = (const float*)d_in[21];
    const float* fc1_xt_b   = (const float*)d_in[22];
    const float* fc1_w      = (const float*)d_in[23];
    const float* fc1_b      = (const float*)d_in[24];
    const float* fc2_w      = (const float*)d_in[25];
    const float* fc2_b      = (const float*)d_in[26];
    const float* out_w      = (const float*)d_in[27];
    const float* out_b      = (const float*)d_in[28];
    float* out = (float*)d_out;

    char* ws = (char*)d_ws;
    size_t off = 0;
    auto alloc = [&](size_t bytes) -> void* {
        void* p = ws + off;
        off = (off + bytes + 255) & ~(size_t)255;
        return p;
    };
    float* P        = (float*)alloc((size_t)NN * 32 * 4);
    float* AGG      = (float*)alloc((size_t)NN * 32 * 4);   // dead (xt_part span)
    float* Y0       = (float*)alloc((size_t)NN * 32 * 4);
    float* Y1       = (float*)alloc((size_t)NN * 32 * 4);
    float* partials = (float*)alloc((size_t)3125 * 64 * 4);
    float* sums     = (float*)alloc(64 * 4);
    float* XG       = (float*)alloc((size_t)BB * 32 * 4);
    float* XD       = (float*)alloc((size_t)BB * 128 * 4);
    float* Mt       = (float*)alloc((size_t)26 * 256 * 4);
    float* XT       = (float*)alloc((size_t)BB * 128 * 4);
    float* XC       = (float*)alloc((size_t)BB * COMB * 4);
    float* XC2      = (float*)alloc((size_t)BB * 1024 * 4);
    float* XC3      = (float*)alloc((size_t)BB * 256 * 4);
    float* C        = (float*)alloc((size_t)BB * FLATN * 4);  // 130 MB

    // Aliases (single stream => strictly ordered):
    //  - xt_part (63*1024*128 f32 = 33MB) overlays P+AGG+Y0[0..7.4MB); dead until first gin_gemm1.
    //  - fc1_part (16.8MB) at C+0, fc2_part (8.4MB) at C+17MB — used only AFTER xt GEMM consumed C.
    //  - CSR at C+48MB — built after xt GEMM, read through the GIN phase; disjoint from fc parts.
    float* xt_part  = P;
    float* fc1_part = C;
    float* fc2_part = C + (size_t)17 * 1024 * 1024 / 4;
    char*  csr      = (char*)C + (size_t)48 * 1024 * 1024;
    int* deg    = (int*)csr;
    int* cursor = deg + NN;
    int* scanex = cursor + NN;
    int* bsums  = scanex + NN;
    int* bexcl  = bsums + 512;
    int* rowptr = bexcl + 512;
    int* eidx   = rowptr + (NN + 2);

    const int* src = edge;
    const int* dst = edge + EE;

    // ---- protein branch (unfused conv + deep-split-K GEMM) ----
    mtable_kernel<<<26, 256, 0, stream>>>(emb, convxt_w, Mt);
    conv_kernel<<<dim3(8, BB), 256, 0, stream>>>(target, Mt, convxt_b, C);
    gemm_v3<128><<<dim3(16, 1, 63), 256, 0, stream>>>(
        C, fc1_xt_w, xt_part, FLATN, 128, 128, FLATN, 512);
    splitk_reduce<<<128, 256, 0, stream>>>(xt_part, fc1_xt_b, XT, BB * 128, 128, 63);

    // ---- CSR build (C GEMM-input role done; CSR lives at C+48MB) ----
    hipMemsetAsync(deg, 0, (size_t)2 * NN * 4, stream);   // deg + cursor
    hist_kernel<<<1563, 256, 0, stream>>>(dst, deg);
    scan1_kernel<<<NB_SC, 256, 0, stream>>>(deg, scanex, bsums);
    scan2_kernel<<<1, 512, 0, stream>>>(bsums, bexcl);
    rowptr_kernel<<<NB_SC, 256, 0, stream>>>(scanex, bexcl, rowptr);
    fill_kernel<<<1563, 256, 0, stream>>>(src, dst, rowptr, cursor, eidx);

    // ---- GIN layer 1 (78 -> 32) ----
    gin_gemm1<78, false><<<3125, 256, 0, stream>>>(x, w1a, P, nullptr, nullptr, nullptr);
    gin_gather_gemm2<<<3125, 256, 0, stream>>>(rowptr, eidx, P, w1b, b1a, b1b, Y0, partials);
    stat_reduce<<<64, 256, 0, stream>>>(partials, sums);

    // ---- GIN layers 2..5 ----
    float* yin = Y0; float* yout = Y1;
    for (int li = 0; li < 4; ++li) {
        gin_gemm1<32, true><<<3125, 256, 0, stream>>>(
            yin, gw_a + li * 1024, P, sums, bn_gamma + li * 32, bn_beta + li * 32);
        gin_gather_gemm2<<<3125, 256, 0, stream>>>(
            rowptr, eidx, P, gw_b + li * 1024, gb_a + li * 32, gb_b + li * 32, yout, partials);
        stat_reduce<<<64, 256, 0, stream>>>(partials, sums);
        float* t = yin; yin = yout; yout = t;
    }

    // ---- pool + fc1_xd (applies layer-5 BN affine on load) ----
    hipMemsetAsync(XG, 0, (size_t)BB * 32 * 4, stream);
    pool_kernel<<<12500, 256, 0, stream>>>(yin, batch, sums, bn_gamma + 4 * 32, bn_beta + 4 * 32, XG);
    fc_xd_kernel<<<BB, 128, 0, stream>>>(XG, fc1_xd_w, fc1_xd_b, XD);

    // ---- combine + MLP head ----
    concat_kernel<<<9216, 256, 0, stream>>>(XD, XT, drug_lm, protein_lm, XC);
    gemm_v3<128><<<dim3(16, 8, 4), 256, 0, stream>>>(
        XC, fc1_w, fc1_part, COMB, 1024, 1024, COMB, 576);
    splitk_reduce<<<1024, 256, 0, stream>>>(fc1_part, fc1_b, XC2, BB * 1024, 1024, 4);
    gemm_v3<128><<<dim3(16, 2, 8), 256, 0, stream>>>(
        XC2, fc2_w, fc2_part, 1024, 256, 256, 1024, 128);
    splitk_reduce<<<256, 256, 0, stream>>>(fc2_part, fc2_b, XC3, BB * 256, 256, 8);
    out_kernel<<<256, 256, 0, stream>>>(XC3, out_w, out_b, out);
}